// Round 7
// baseline (578.985 us; speedup 1.0000x reference)
//
#include <hip/hip_runtime.h>
#include <hip/hip_bf16.h>

#define IN_CH 64
#define HC 128          // HEADS * OUT_CH
#define NHEAD 4
#define NEG 0.2f
#define CAPB 64         // bucket capacity per node (Poisson(16) max-deg ~45; overflow list covers rest)
#define OF_MAX 65536    // overflow capacity (structurally safe guard)
#define RS 512          // nodes per region
#define RSH 9
#define K_MAX 200       // max regions binned in LDS (196 used); beyond -> direct fallback
#define CAPL 64         // LDS bin capacity (one wave-width flush)
#define CAPF 12288      // per-region FIFO capacity (avg load ~8163, max ~8600)

__device__ __forceinline__ float leaky(float v) { return v >= 0.f ? v : NEG * v; }
__device__ __forceinline__ float bf2f(unsigned short u) {
    return __uint_as_float(((unsigned int)u) << 16);
}

// Two nodes per 256-thread block: h[n] = x[n] @ W (bf16 out); a_src/a_dst fp32.
__global__ void __launch_bounds__(256) k_transform(
        const float* __restrict__ x, const float* __restrict__ W,
        const float* __restrict__ att_src, const float* __restrict__ att_dst,
        __hip_bfloat16* __restrict__ h_bf, float* __restrict__ a_src,
        float* __restrict__ a_dst, int N) {
    const int t = threadIdx.x;
    const int half = t >> 7;             // 0/1
    const int tc = t & 127;              // channel
    const int n = blockIdx.x * 2 + half;
    if (n >= N) return;
    __shared__ float xs[2][IN_CH];
    if (tc < IN_CH) xs[half][tc] = x[(size_t)n * IN_CH + tc];
    __syncthreads();
    float acc = 0.f;
#pragma unroll
    for (int k = 0; k < IN_CH; ++k)
        acc = fmaf(xs[half][k], W[k * HC + tc], acc);
    h_bf[(size_t)n * HC + tc] = __float2bfloat16(acc);

    float ps = acc * att_src[tc];
    float pd = acc * att_dst[tc];
#pragma unroll
    for (int off = 16; off > 0; off >>= 1) {
        ps += __shfl_down(ps, off, 32);
        pd += __shfl_down(pd, off, 32);
    }
    if ((tc & 31) == 0) {
        a_src[n * NHEAD + (tc >> 5)] = ps;
        a_dst[n * NHEAD + (tc >> 5)] = pd;
    }
}

__device__ __forceinline__ void direct_insert(int node, int s, int* ncnt, int* srcbuf,
                                              int* oflow, int* oflow_cnt) {
    const int p = atomicAdd(&ncnt[node], 1);
    if (p < CAPB) srcbuf[(size_t)node * CAPB + p] = s;
    else {
        const int q = atomicAdd(oflow_cnt, 1);
        if (q < OF_MAX) { oflow[2 * q] = node; oflow[2 * q + 1] = s; }
    }
}

// Phase 1: LDS-binned region partitioning. Coalesced edge reads; coalesced
// 64-entry flushes to per-region FIFOs (one global atomic per flush).
__global__ void __launch_bounds__(256) k_bin(
        const int* __restrict__ src, const int* __restrict__ dst,
        int* __restrict__ fifo, int* __restrict__ fifo_cnt,
        int* __restrict__ ncnt, int* __restrict__ srcbuf,
        int* __restrict__ oflow, int* __restrict__ oflow_cnt,
        int E, int nBlocks) {
    __shared__ int bins[K_MAX][CAPL];
    __shared__ int bcnt[K_MAX];
    __shared__ int flag;
    const int t = threadIdx.x;
    const int lane = t & 63, w = t >> 6;
    for (int i = t; i < K_MAX; i += 256) bcnt[i] = 0;
    if (t == 0) flag = 0;
    __syncthreads();

    const int chunk = (E + nBlocks - 1) / nBlocks;
    const int lo = blockIdx.x * chunk;
    const int hi = min(lo + chunk, E);

    for (int base = lo; base < hi; base += 256) {
        const int e = base + t;
        bool pending = (e < hi);
        int bin = 0; int pk = 0;
        if (pending) {
            const int s = src[e], d = dst[e];
            bin = d >> RSH;
            if (bin >= K_MAX || s >= (1 << 17)) {       // structural fallback
                direct_insert(d, s, ncnt, srcbuf, oflow, oflow_cnt);
                pending = false;
            } else {
                pk = ((d & (RS - 1)) << 17) | s;
            }
        }
        while (true) {
            if (pending) {
                const int pos = atomicAdd(&bcnt[bin], 1);
                if (pos < CAPL) { bins[bin][pos] = pk; pending = false; }
                else flag = 1;
            }
            __syncthreads();
            if (flag == 0) break;                        // block-uniform
            // flush full bins; wave b%4 handles bin b
            for (int b = w; b < K_MAX; b += 4) {
                const int c = bcnt[b];                   // wave-uniform broadcast
                if (c >= CAPL) {
                    int fbase = 0;
                    if (lane == 0) fbase = atomicAdd(&fifo_cnt[b], CAPL);
                    fbase = __shfl(fbase, 0, 64);
                    const int v = bins[b][lane];
                    const int gi = fbase + lane;
                    if (gi < CAPF) fifo[(size_t)b * CAPF + gi] = v;
                    else direct_insert((b << RSH) + (v >> 17), v & 0x1FFFF,
                                       ncnt, srcbuf, oflow, oflow_cnt);
                    if (lane == 0) bcnt[b] = 0;
                }
            }
            __syncthreads();
            if (t == 0) flag = 0;
            __syncthreads();
        }
    }
    // final flush of partial bins
    for (int b = w; b < K_MAX; b += 4) {
        const int c = min(bcnt[b], CAPL);
        if (c > 0) {
            int fbase = 0;
            if (lane == 0) fbase = atomicAdd(&fifo_cnt[b], c);
            fbase = __shfl(fbase, 0, 64);
            if (lane < c) {
                const int v = bins[b][lane];
                const int gi = fbase + lane;
                if (gi < CAPF) fifo[(size_t)b * CAPF + gi] = v;
                else direct_insert((b << RSH) + (v >> 17), v & 0x1FFFF,
                                   ncnt, srcbuf, oflow, oflow_cnt);
            }
        }
    }
}

// Phase 2: one block per region; scatter into the region's L2-resident
// bucket window (each cnt/bucket line written by exactly one block).
__global__ void __launch_bounds__(256) k_scatter(
        const int* __restrict__ fifo, const int* __restrict__ fifo_cnt,
        int* __restrict__ ncnt, int* __restrict__ srcbuf,
        int* __restrict__ oflow, int* __restrict__ oflow_cnt) {
    const int r = blockIdx.x;
    const int c = min(fifo_cnt[r], CAPF);
    const int nb = r << RSH;
    for (int i = threadIdx.x; i < c; i += 256) {
        const int v = fifo[(size_t)r * CAPF + i];
        direct_insert(nb + (v >> 17), v & 0x1FFFF, ncnt, srcbuf, oflow, oflow_cnt);
    }
}

// ---------------- fused per-node kernel: one wave per node ----------------
__global__ void __launch_bounds__(256) k_node(
        const int* __restrict__ ncnt, const int* __restrict__ srcbuf,
        const int* __restrict__ oflow, const int* __restrict__ oflow_cnt,
        const float* __restrict__ a_src, const float* __restrict__ a_dst,
        const unsigned short* __restrict__ h_bf, const float* __restrict__ bias,
        float* __restrict__ out, int N) {
    const int lane = threadIdx.x & 63;
    const int w = threadIdx.x >> 6;
    int n = blockIdx.x * 4 + w;
    n = min(n, N - 1);                    // keep barriers uniform; dup writes benign
    const size_t start = (size_t)n * CAPB;
    const int deg = min(ncnt[n], CAPB);
    const int oc = min(*oflow_cnt, OF_MAX);   // wave-uniform; 0 in practice
    const int myh = lane & 3;

    __shared__ float s_ex[4][CAPB * NHEAD];
    __shared__ int   s_src[4][CAPB];

    const float ad  = a_dst[n * NHEAD + myh];
    const float asf = a_src[n * NHEAD + myh];

    // pass A: gather a_src once into LDS; max of raw a_src (leaky monotone => fold at end)
    float mxas = asf;
    for (int j = lane >> 2; j < deg; j += 16) {
        const int s = srcbuf[start + j];
        const float as = a_src[s * NHEAD + myh];
        s_ex[w][j * NHEAD + myh] = as;
        if (myh == 0) s_src[w][j] = s;
        mxas = fmaxf(mxas, as);
    }
    for (int j = lane >> 2; j < oc; j += 16) {            // overflow (normally empty)
        if (oflow[2 * j] == n)
            mxas = fmaxf(mxas, a_src[oflow[2 * j + 1] * NHEAD + myh]);
    }
#pragma unroll
    for (int off = 4; off < 64; off <<= 1) mxas = fmaxf(mxas, __shfl_xor(mxas, off, 64));
    const float m = leaky(mxas + ad);
    __syncthreads();

    // pass B: exp(e - m) into LDS; per-head sum
    float sm = (lane < 4) ? __expf(leaky(asf + ad) - m) : 0.f;
    for (int j = lane >> 2; j < deg; j += 16) {
        const float as = s_ex[w][j * NHEAD + myh];
        const float ex = __expf(leaky(as + ad) - m);
        s_ex[w][j * NHEAD + myh] = ex;
        sm += ex;
    }
    for (int j = lane >> 2; j < oc; j += 16) {            // overflow (normally empty)
        if (oflow[2 * j] == n)
            sm += __expf(leaky(a_src[oflow[2 * j + 1] * NHEAD + myh] + ad) - m);
    }
#pragma unroll
    for (int off = 4; off < 64; off <<= 1) sm += __shfl_xor(sm, off, 64);
    const float r = 1.f / (sm + 1e-16f);
    __syncthreads();

    // pass C: lane handles channels {2*lane, 2*lane+1}; head = lane>>4
    const int hh = lane >> 4;
    const float rh  = __shfl(r, hh, 64);
    const float mh  = __shfl(m, hh, 64);
    const float adh = __shfl(ad, hh, 64);

    float acc0 = 0.f, acc1 = 0.f;
    for (int j = 0; j < deg; ++j) {
        const int s = s_src[w][j];
        const float al = s_ex[w][j * NHEAD + hh] * rh;
        const ushort2 hv = *((const ushort2*)(h_bf + (size_t)s * HC) + lane);
        acc0 = fmaf(al, bf2f(hv.x), acc0);
        acc1 = fmaf(al, bf2f(hv.y), acc1);
    }
    for (int j = 0; j < oc; ++j) {                        // overflow (normally empty)
        if (oflow[2 * j] == n) {
            const int s = oflow[2 * j + 1];
            const float al = __expf(leaky(a_src[s * NHEAD + hh] + adh) - mh) * rh;
            const ushort2 hv = *((const ushort2*)(h_bf + (size_t)s * HC) + lane);
            acc0 = fmaf(al, bf2f(hv.x), acc0);
            acc1 = fmaf(al, bf2f(hv.y), acc1);
        }
    }
    // self loop
    {
        const float als = __expf(leaky(asf + ad) - m) * r;   // valid per myh
        const float alh = __shfl(als, hh, 64);
        const ushort2 hv = *((const ushort2*)(h_bf + (size_t)n * HC) + lane);
        acc0 = fmaf(alh, bf2f(hv.x), acc0);
        acc1 = fmaf(alh, bf2f(hv.y), acc1);
    }

    // bias + log_softmax over 128 channels
    float v0 = acc0 + bias[2 * lane];
    float v1 = acc1 + bias[2 * lane + 1];
    float mxv = fmaxf(v0, v1);
#pragma unroll
    for (int off = 1; off < 64; off <<= 1) mxv = fmaxf(mxv, __shfl_xor(mxv, off, 64));
    float se = __expf(v0 - mxv) + __expf(v1 - mxv);
#pragma unroll
    for (int off = 1; off < 64; off <<= 1) se += __shfl_xor(se, off, 64);
    const float lse = mxv + __logf(se);
    float2* op = (float2*)(out + (size_t)n * HC) + lane;
    *op = make_float2(v0 - lse, v1 - lse);
}

extern "C" void kernel_launch(void* const* d_in, const int* in_sizes, int n_in,
                              void* d_out, int out_size, void* d_ws, size_t ws_size,
                              hipStream_t stream) {
    const float* x       = (const float*)d_in[0];
    const int*   ei      = (const int*)d_in[1];
    const float* W       = (const float*)d_in[2];
    const float* att_src = (const float*)d_in[3];
    const float* att_dst = (const float*)d_in[4];
    const float* bias    = (const float*)d_in[5];
    float* out = (float*)d_out;

    const int N = in_sizes[0] / IN_CH;     // 100000
    const int E = in_sizes[1] / 2;         // 1600000
    const int* src = ei;
    const int* dst = ei + E;
    const int K = (N + RS - 1) >> RSH;     // 196 regions

    char* wsb = (char*)d_ws;
    __hip_bfloat16* h_bf = (__hip_bfloat16*)wsb;    wsb += (size_t)N * HC * 2;        // 25.6 MB
    float* a_src  = (float*)wsb;                    wsb += (size_t)N * NHEAD * 4;     // 1.6 MB
    float* a_dst  = (float*)wsb;                    wsb += (size_t)N * NHEAD * 4;     // 1.6 MB
    // zeroed region: ncnt | fifo_cnt | oflow_cnt (contiguous)
    int*   ncnt     = (int*)wsb;                    wsb += (size_t)N * 4;             // 0.4 MB
    int*   fifo_cnt = (int*)wsb;                    wsb += (size_t)K_MAX * 4;
    int*   oflow_cnt= (int*)wsb;                    wsb += 16 * 4;
    int*   oflow  = (int*)wsb;                      wsb += (size_t)OF_MAX * 2 * 4;    // 0.5 MB
    int*   srcbuf = (int*)wsb;                      wsb += (size_t)N * CAPB * 4;      // 25.6 MB
    int*   fifo   = (int*)wsb;                      wsb += (size_t)K * CAPF * 4;      // 9.6 MB

    hipMemsetAsync(ncnt, 0, ((size_t)N + K_MAX + 16) * 4, stream);

    k_transform<<<(N + 1) / 2, 256, 0, stream>>>(x, W, att_src, att_dst, h_bf,
                                                 a_src, a_dst, N);
    const int NB1 = 256;
    k_bin<<<NB1, 256, 0, stream>>>(src, dst, fifo, fifo_cnt, ncnt, srcbuf,
                                   oflow, oflow_cnt, E, NB1);
    k_scatter<<<K, 256, 0, stream>>>(fifo, fifo_cnt, ncnt, srcbuf, oflow, oflow_cnt);
    k_node<<<(N + 3) / 4, 256, 0, stream>>>(ncnt, srcbuf, oflow, oflow_cnt,
                                            a_src, a_dst,
                                            (const unsigned short*)h_bf, bias, out, N);
}

// Round 8
// 425.474 us; speedup vs baseline: 1.3608x; 1.3608x over previous
//
#include <hip/hip_runtime.h>
#include <hip/hip_bf16.h>

#define IN_CH 64
#define HC 128          // HEADS * OUT_CH
#define NHEAD 4
#define NEG 0.2f
#define BSTRIDE 32      // ints per node bucket line: [cnt | 31 src slots] = 128 B
#define CAPB 31         // inline slots per node (P(deg>31)~3e-5; overflow list covers)
#define OF_MAX 65536    // overflow capacity (structural guard)

__device__ __forceinline__ float leaky(float v) { return v >= 0.f ? v : NEG * v; }
__device__ __forceinline__ float bf2f(unsigned short u) {
    return __uint_as_float(((unsigned int)u) << 16);
}

// Two nodes per 256-thread block: h[n] = x[n] @ W (bf16 out); a_src/a_dst fp32.
__global__ void __launch_bounds__(256) k_transform(
        const float* __restrict__ x, const float* __restrict__ W,
        const float* __restrict__ att_src, const float* __restrict__ att_dst,
        __hip_bfloat16* __restrict__ h_bf, float* __restrict__ a_src,
        float* __restrict__ a_dst, int N) {
    const int t = threadIdx.x;
    const int half = t >> 7;             // 0/1
    const int tc = t & 127;              // channel
    const int n = blockIdx.x * 2 + half;
    if (n >= N) return;
    __shared__ float xs[2][IN_CH];
    if (tc < IN_CH) xs[half][tc] = x[(size_t)n * IN_CH + tc];
    __syncthreads();
    float acc = 0.f;
#pragma unroll
    for (int k = 0; k < IN_CH; ++k)
        acc = fmaf(xs[half][k], W[k * HC + tc], acc);
    h_bf[(size_t)n * HC + tc] = __float2bfloat16(acc);

    float ps = acc * att_src[tc];
    float pd = acc * att_dst[tc];
#pragma unroll
    for (int off = 16; off > 0; off >>= 1) {
        ps += __shfl_down(ps, off, 32);
        pd += __shfl_down(pd, off, 32);
    }
    if ((tc & 31) == 0) {
        a_src[n * NHEAD + (tc >> 5)] = ps;
        a_dst[n * NHEAD + (tc >> 5)] = pd;
    }
}

// Bucket fill with inline counters: one 128B line per node holds cnt + 31 srcs.
__global__ void __launch_bounds__(256) k_bucket(
        const int* __restrict__ src, const int* __restrict__ dst,
        int* __restrict__ bucket,
        int* __restrict__ oflow, int* __restrict__ oflow_cnt, int E) {
    const int base = (blockIdx.x * blockDim.x + threadIdx.x) * 4;
    if (base + 3 < E) {
        const int4 s4 = *(const int4*)(src + base);
        const int4 d4 = *(const int4*)(dst + base);
        const int ss[4] = {s4.x, s4.y, s4.z, s4.w};
        const int dd[4] = {d4.x, d4.y, d4.z, d4.w};
#pragma unroll
        for (int k = 0; k < 4; ++k) {
            const int p = atomicAdd(&bucket[(size_t)dd[k] * BSTRIDE], 1);
            if (p < CAPB) bucket[(size_t)dd[k] * BSTRIDE + 1 + p] = ss[k];
            else {
                const int q = atomicAdd(oflow_cnt, 1);
                if (q < OF_MAX) { oflow[2 * q] = dd[k]; oflow[2 * q + 1] = ss[k]; }
            }
        }
    } else {
        for (int e = base; e < E; ++e) {
            const int s = src[e], d = dst[e];
            const int p = atomicAdd(&bucket[(size_t)d * BSTRIDE], 1);
            if (p < CAPB) bucket[(size_t)d * BSTRIDE + 1 + p] = s;
            else {
                const int q = atomicAdd(oflow_cnt, 1);
                if (q < OF_MAX) { oflow[2 * q] = d; oflow[2 * q + 1] = s; }
            }
        }
    }
}

// ---------------- fused per-node kernel: one wave per node ----------------
__global__ void __launch_bounds__(256) k_node(
        const int* __restrict__ bucket,
        const int* __restrict__ oflow, const int* __restrict__ oflow_cnt,
        const float* __restrict__ a_src, const float* __restrict__ a_dst,
        const unsigned short* __restrict__ h_bf, const float* __restrict__ bias,
        float* __restrict__ out, int N) {
    const int lane = threadIdx.x & 63;
    const int w = threadIdx.x >> 6;
    int n = blockIdx.x * 4 + w;
    n = min(n, N - 1);                    // keep barriers uniform; dup writes benign
    const size_t bb = (size_t)n * BSTRIDE;
    const int deg = min(bucket[bb], CAPB);
    const int oc = min(*oflow_cnt, OF_MAX);   // wave-uniform; ~0 in practice
    const int myh = lane & 3;

    __shared__ float s_ex[4][BSTRIDE * NHEAD];
    __shared__ int   s_src[4][BSTRIDE];

    const float ad  = a_dst[n * NHEAD + myh];
    const float asf = a_src[n * NHEAD + myh];

    // pass A: gather a_src once into LDS; max of raw a_src (leaky monotone => fold at end)
    float mxas = asf;
    for (int j = lane >> 2; j < deg; j += 16) {
        const int s = bucket[bb + 1 + j];
        const float as = a_src[s * NHEAD + myh];
        s_ex[w][j * NHEAD + myh] = as;
        if (myh == 0) s_src[w][j] = s;
        mxas = fmaxf(mxas, as);
    }
    for (int j = lane >> 2; j < oc; j += 16) {            // overflow (tiny)
        if (oflow[2 * j] == n)
            mxas = fmaxf(mxas, a_src[oflow[2 * j + 1] * NHEAD + myh]);
    }
#pragma unroll
    for (int off = 4; off < 64; off <<= 1) mxas = fmaxf(mxas, __shfl_xor(mxas, off, 64));
    const float m = leaky(mxas + ad);
    __syncthreads();

    // pass B: exp(e - m) into LDS; per-head sum
    float sm = (lane < 4) ? __expf(leaky(asf + ad) - m) : 0.f;
    for (int j = lane >> 2; j < deg; j += 16) {
        const float as = s_ex[w][j * NHEAD + myh];
        const float ex = __expf(leaky(as + ad) - m);
        s_ex[w][j * NHEAD + myh] = ex;
        sm += ex;
    }
    for (int j = lane >> 2; j < oc; j += 16) {            // overflow (tiny)
        if (oflow[2 * j] == n)
            sm += __expf(leaky(a_src[oflow[2 * j + 1] * NHEAD + myh] + ad) - m);
    }
#pragma unroll
    for (int off = 4; off < 64; off <<= 1) sm += __shfl_xor(sm, off, 64);
    const float r = 1.f / (sm + 1e-16f);
    __syncthreads();

    // pass C: lane handles channels {2*lane, 2*lane+1}; head = lane>>4
    const int hh = lane >> 4;
    const float rh  = __shfl(r, hh, 64);
    const float mh  = __shfl(m, hh, 64);
    const float adh = __shfl(ad, hh, 64);

    float acc0 = 0.f, acc1 = 0.f;
    for (int j = 0; j < deg; ++j) {
        const int s = s_src[w][j];
        const float al = s_ex[w][j * NHEAD + hh] * rh;
        const ushort2 hv = *((const ushort2*)(h_bf + (size_t)s * HC) + lane);
        acc0 = fmaf(al, bf2f(hv.x), acc0);
        acc1 = fmaf(al, bf2f(hv.y), acc1);
    }
    for (int j = 0; j < oc; ++j) {                        // overflow (tiny)
        if (oflow[2 * j] == n) {
            const int s = oflow[2 * j + 1];
            const float al = __expf(leaky(a_src[s * NHEAD + hh] + adh) - mh) * rh;
            const ushort2 hv = *((const ushort2*)(h_bf + (size_t)s * HC) + lane);
            acc0 = fmaf(al, bf2f(hv.x), acc0);
            acc1 = fmaf(al, bf2f(hv.y), acc1);
        }
    }
    // self loop
    {
        const float als = __expf(leaky(asf + ad) - m) * r;   // valid per myh
        const float alh = __shfl(als, hh, 64);
        const ushort2 hv = *((const ushort2*)(h_bf + (size_t)n * HC) + lane);
        acc0 = fmaf(alh, bf2f(hv.x), acc0);
        acc1 = fmaf(alh, bf2f(hv.y), acc1);
    }

    // bias + log_softmax over 128 channels
    float v0 = acc0 + bias[2 * lane];
    float v1 = acc1 + bias[2 * lane + 1];
    float mxv = fmaxf(v0, v1);
#pragma unroll
    for (int off = 1; off < 64; off <<= 1) mxv = fmaxf(mxv, __shfl_xor(mxv, off, 64));
    float se = __expf(v0 - mxv) + __expf(v1 - mxv);
#pragma unroll
    for (int off = 1; off < 64; off <<= 1) se += __shfl_xor(se, off, 64);
    const float lse = mxv + __logf(se);
    float2* op = (float2*)(out + (size_t)n * HC) + lane;
    *op = make_float2(v0 - lse, v1 - lse);
}

extern "C" void kernel_launch(void* const* d_in, const int* in_sizes, int n_in,
                              void* d_out, int out_size, void* d_ws, size_t ws_size,
                              hipStream_t stream) {
    const float* x       = (const float*)d_in[0];
    const int*   ei      = (const int*)d_in[1];
    const float* W       = (const float*)d_in[2];
    const float* att_src = (const float*)d_in[3];
    const float* att_dst = (const float*)d_in[4];
    const float* bias    = (const float*)d_in[5];
    float* out = (float*)d_out;

    const int N = in_sizes[0] / IN_CH;     // 100000
    const int E = in_sizes[1] / 2;         // 1600000
    const int* src = ei;
    const int* dst = ei + E;

    char* wsb = (char*)d_ws;
    __hip_bfloat16* h_bf = (__hip_bfloat16*)wsb;    wsb += (size_t)N * HC * 2;        // 25.6 MB
    float* a_src  = (float*)wsb;                    wsb += (size_t)N * NHEAD * 4;     // 1.6 MB
    float* a_dst  = (float*)wsb;                    wsb += (size_t)N * NHEAD * 4;     // 1.6 MB
    int*   bucket = (int*)wsb;                      wsb += (size_t)N * BSTRIDE * 4;   // 12.8 MB
    int*   oflow_cnt = (int*)wsb;                   wsb += 32 * 4;
    int*   oflow  = (int*)wsb;                      wsb += (size_t)OF_MAX * 2 * 4;    // 0.5 MB

    // zero buckets (inline counters) + oflow_cnt in one contiguous memset
    hipMemsetAsync(bucket, 0, ((size_t)N * BSTRIDE + 32) * 4, stream);

    k_transform<<<(N + 1) / 2, 256, 0, stream>>>(x, W, att_src, att_dst, h_bf,
                                                 a_src, a_dst, N);
    k_bucket<<<(E / 4 + 255) / 256, 256, 0, stream>>>(src, dst, bucket,
                                                      oflow, oflow_cnt, E);
    k_node<<<(N + 3) / 4, 256, 0, stream>>>(bucket, oflow, oflow_cnt,
                                            a_src, a_dst,
                                            (const unsigned short*)h_bf, bias, out, N);
}